// Round 10
// baseline (1177.960 us; speedup 1.0000x reference)
//
#include <hip/hip_runtime.h>
#include <hip/hip_bf16.h>

// ---------------- problem constants ----------------
#define NB 32
#define T0_ 1000
#define IN_DIM_ 40
#define OUT_DIM_ 512
#define TDNN5_ 1500
#define T1_ 996
#define T2_ 992
#define T3_ 986
#define T4_ 985
#define T5_ 984
#define NCLS_ 1000

#define TM 128
#define TN 64
#define KB 32

typedef __attribute__((ext_vector_type(8))) short short8_t;
typedef __attribute__((ext_vector_type(4))) float float4_t;

#define GLDS16(gp, lp) __builtin_amdgcn_global_load_lds( \
    (__attribute__((address_space(1))) void*)(gp), \
    (__attribute__((address_space(3))) void*)(lp), 16, 0, 0)

__device__ __forceinline__ unsigned short f2bf(float f) {
    unsigned int u = __float_as_uint(f);
    unsigned int r = u + 0x7FFFu + ((u >> 16) & 1u);
    return (unsigned short)(r >> 16);
}
__device__ __forceinline__ float bf2f(unsigned short h) {
    return __uint_as_float((unsigned int)h << 16);
}

// ---------------- fused prep kernel ----------------
// segments: 0 xsplit | 1..5 wsplit L1..L5 | 6 zero gsum+gsq
#define S0E 1280000L
#define S1E 1394688L   // +512*224
#define S2E 2705408L   // +512*2560
#define S3E 4540416L   // +512*3584
#define S4E 4802560L   // +512*512
#define S5E 5588992L   // +1536*512
#define S6E 5684992L   // +96000
__device__ __forceinline__ void wsplit_one(const float* __restrict__ src,
                                           unsigned short* __restrict__ whi,
                                           unsigned short* __restrict__ wlo,
                                           long idx, int N, int K, int Kpad,
                                           int Ci, int W) {
    int n = (int)(idx / Kpad);
    int k = (int)(idx % Kpad);
    float v = 0.f;
    if (n < N && k < K) {
        int w = k / Ci, i = k % Ci;
        v = src[((size_t)n * Ci + i) * W + w];
    }
    unsigned short h = f2bf(v);
    whi[idx] = h;
    wlo[idx] = f2bf(v - bf2f(h));
}

__global__ __launch_bounds__(256) void prep_all(
    const float* __restrict__ x,
    const float* __restrict__ k1, const float* __restrict__ k2,
    const float* __restrict__ k3, const float* __restrict__ k4,
    const float* __restrict__ k5,
    unsigned short* __restrict__ xhi, unsigned short* __restrict__ xlo,
    unsigned short* __restrict__ w1h, unsigned short* __restrict__ w1l,
    unsigned short* __restrict__ w2h, unsigned short* __restrict__ w2l,
    unsigned short* __restrict__ w3h, unsigned short* __restrict__ w3l,
    unsigned short* __restrict__ w4h, unsigned short* __restrict__ w4l,
    unsigned short* __restrict__ w5h, unsigned short* __restrict__ w5l,
    float* __restrict__ gsum) {
    long idx = (long)blockIdx.x * 256 + threadIdx.x;
    if (idx < S0E) {
        int i = (int)(idx % IN_DIM_);
        int t = (int)((idx / IN_DIM_) % T0_);
        int b = (int)(idx / (IN_DIM_ * T0_));
        float v = x[((size_t)b * IN_DIM_ + i) * T0_ + t];
        unsigned short h = f2bf(v);
        xhi[idx] = h;
        xlo[idx] = f2bf(v - bf2f(h));
    } else if (idx < S1E) {
        wsplit_one(k1, w1h, w1l, idx - S0E, 512, 200, 224, IN_DIM_, 5);
    } else if (idx < S2E) {
        wsplit_one(k2, w2h, w2l, idx - S1E, 512, 2560, 2560, 512, 5);
    } else if (idx < S3E) {
        wsplit_one(k3, w3h, w3l, idx - S2E, 512, 3584, 3584, 512, 7);
    } else if (idx < S4E) {
        wsplit_one(k4, w4h, w4l, idx - S3E, 512, 512, 512, 512, 1);
    } else if (idx < S5E) {
        wsplit_one(k5, w5h, w5l, idx - S4E, 1500, 512, 512, 512, 1);
    } else if (idx < S6E) {
        gsum[idx - S5E] = 0.f;   // gsum||gsq contiguous
    }
}

// ---------------- L1 kernel: round-5/6 proven conv (Ci=40) ----------------
template <bool STATS>
__global__ __launch_bounds__(256, 3) void conv_mfma(
    const unsigned short* __restrict__ in_hi, const unsigned short* __restrict__ in_lo,
    const unsigned short* __restrict__ w_hi,  const unsigned short* __restrict__ w_lo,
    const float* __restrict__ bias,
    unsigned short* __restrict__ out_hi, unsigned short* __restrict__ out_lo,
    float* __restrict__ gsum, float* __restrict__ gsq,
    int GY, int M, int N, int Kpad, int Ci, int rowOff, long inB, long outB) {

    __shared__ unsigned short As_hi[TM][KB];
    __shared__ unsigned short As_lo[TM][KB];
    __shared__ unsigned short Bs_hi[TN][KB];
    __shared__ unsigned short Bs_lo[TN][KB];

    const int tid  = threadIdx.x;
    const int lane = tid & 63;
    const int wav  = tid >> 6;
    const int lr   = lane & 15;
    const int lq   = lane >> 4;

    const int bid = blockIdx.x;
    const int n0 = (bid % GY) * TN;
    const int rem = bid / GY;
    const int t0 = (rem & 7) * TM;
    const int b  = rem >> 3;

    const int sr = lane >> 2;
    const int sc = (lane & 3) * 8;
    const unsigned short* Ah = in_hi + (size_t)b * inB;
    const unsigned short* Al = in_lo + (size_t)b * inB;
    const size_t gA0 = (size_t)(t0 + rowOff + 32 * wav + sr) * Ci + sc;
    const size_t gA1 = (size_t)(t0 + rowOff + 32 * wav + 16 + sr) * Ci + sc;
    const size_t gB  = (size_t)(n0 + 16 * wav + sr) * Kpad + sc;
    unsigned short* ldsA0h = &As_hi[32 * wav][0];
    unsigned short* ldsA1h = &As_hi[32 * wav + 16][0];
    unsigned short* ldsA0l = &As_lo[32 * wav][0];
    unsigned short* ldsA1l = &As_lo[32 * wav + 16][0];
    unsigned short* ldsBh  = &Bs_hi[16 * wav][0];
    unsigned short* ldsBl  = &Bs_lo[16 * wav][0];

    float4_t acc[2][4];
    #pragma unroll
    for (int mi = 0; mi < 2; ++mi)
        #pragma unroll
        for (int nj = 0; nj < 4; ++nj) acc[mi][nj] = (float4_t)0.f;

    for (int k0 = 0; k0 < Kpad; k0 += KB) {
        __syncthreads();
        GLDS16(Ah + gA0 + k0, ldsA0h);
        GLDS16(Ah + gA1 + k0, ldsA1h);
        GLDS16(Al + gA0 + k0, ldsA0l);
        GLDS16(Al + gA1 + k0, ldsA1l);
        GLDS16(w_hi + gB + k0, ldsBh);
        GLDS16(w_lo + gB + k0, ldsBl);
        asm volatile("s_waitcnt vmcnt(0)" ::: "memory");
        __syncthreads();

        short8_t ahf[2], alf[2], bhf[4], blf[4];
        #pragma unroll
        for (int mi = 0; mi < 2; ++mi) {
            int r = wav * 32 + mi * 16 + lr;
            ahf[mi] = *(const short8_t*)&As_hi[r][lq * 8];
            alf[mi] = *(const short8_t*)&As_lo[r][lq * 8];
        }
        #pragma unroll
        for (int nj = 0; nj < 4; ++nj) {
            bhf[nj] = *(const short8_t*)&Bs_hi[nj * 16 + lr][lq * 8];
            blf[nj] = *(const short8_t*)&Bs_lo[nj * 16 + lr][lq * 8];
        }
        #pragma unroll
        for (int mi = 0; mi < 2; ++mi)
            #pragma unroll
            for (int nj = 0; nj < 4; ++nj) {
                acc[mi][nj] = __builtin_amdgcn_mfma_f32_16x16x32_bf16(ahf[mi], bhf[nj], acc[mi][nj], 0, 0, 0);
                acc[mi][nj] = __builtin_amdgcn_mfma_f32_16x16x32_bf16(alf[mi], bhf[nj], acc[mi][nj], 0, 0, 0);
                acc[mi][nj] = __builtin_amdgcn_mfma_f32_16x16x32_bf16(ahf[mi], blf[nj], acc[mi][nj], 0, 0, 0);
            }
    }

    if (!STATS) {
        #pragma unroll
        for (int mi = 0; mi < 2; ++mi)
            #pragma unroll
            for (int rr = 0; rr < 4; ++rr) {
                int r = t0 + wav * 32 + mi * 16 + lq * 4 + rr;
                if (r < M) {
                    #pragma unroll
                    for (int nj = 0; nj < 4; ++nj) {
                        int n = n0 + nj * 16 + lr;
                        float v = fmaxf(acc[mi][nj][rr] + bias[n], 0.f);
                        unsigned short h = f2bf(v);
                        size_t o = (size_t)b * outB + (size_t)r * N + n;
                        out_hi[o] = h;
                        out_lo[o] = f2bf(v - bf2f(h));
                    }
                }
            }
    } else {
        float cs[4] = {0.f, 0.f, 0.f, 0.f}, cq[4] = {0.f, 0.f, 0.f, 0.f};
        #pragma unroll
        for (int mi = 0; mi < 2; ++mi)
            #pragma unroll
            for (int rr = 0; rr < 4; ++rr) {
                int r = t0 + wav * 32 + mi * 16 + lq * 4 + rr;
                if (r < M) {
                    #pragma unroll
                    for (int nj = 0; nj < 4; ++nj) {
                        int n = n0 + nj * 16 + lr;
                        if (n < N) {
                            float v = fmaxf(acc[mi][nj][rr] + bias[n], 0.f);
                            cs[nj] += v;
                            cq[nj] += v * v;
                        }
                    }
                }
            }
        #pragma unroll
        for (int nj = 0; nj < 4; ++nj) {
            cs[nj] += __shfl_xor(cs[nj], 16);
            cs[nj] += __shfl_xor(cs[nj], 32);
            cq[nj] += __shfl_xor(cq[nj], 16);
            cq[nj] += __shfl_xor(cq[nj], 32);
            int n = n0 + nj * 16 + lr;
            if (lq == 0 && n < N) {
                atomicAdd(&gsum[(size_t)b * N + n], cs[nj]);
                atomicAdd(&gsq[(size_t)b * N + n], cq[nj]);
            }
        }
    }
}

// ---------------- pipelined tap-aware conv for L2-L5 (Ci=512, TM=256) ----------------
// Counted-vmcnt pipeline (T4): B double-buffered, issued 1 phase early; A staged one
// c-block early at the last-tap mid-barrier (overlaps last-tap MFMAs). Per-wave DMA
// issue counts are uniform (A=10 incl. redundant tail, B=2), so vmcnt gates are exact:
//   first-phase gate: vmcnt(2) (drain A + prev B, leave just-issued B)  [fin: vmcnt(0)]
//   end-of-phase:     vmcnt(10) on last-tap (leave A in flight), else vmcnt(0)
// Every barrier is preceded by a "memory"-clobber waitcnt (compiler fence).
// Ledger re-verified by phase-trace for TAPS=1/5/7 (r7/r8): oldest-first retirement
// matches issue order in every phase class; A-clobber gated by lgkmcnt(0)+barrier.
#define AROWS 272
template <int TAPS, bool STATS>
__global__ __launch_bounds__(256, 3) void conv_pipe(
    const unsigned short* __restrict__ in_hi, const unsigned short* __restrict__ in_lo,
    const unsigned short* __restrict__ w_hi,  const unsigned short* __restrict__ w_lo,
    const float* __restrict__ bias,
    unsigned short* __restrict__ out_hi, unsigned short* __restrict__ out_lo,
    float* __restrict__ gsum, float* __restrict__ gsq,
    int GY, int M, int N, int rowOff, long inB, long outB) {

    __shared__ unsigned short Ah_s[AROWS * 32];
    __shared__ unsigned short Al_s[AROWS * 32];
    __shared__ unsigned short Bh_s[2][TN * 32];
    __shared__ unsigned short Bl_s[2][TN * 32];

    const int tid  = threadIdx.x;
    const int lane = tid & 63;
    const int wav  = tid >> 6;
    const int lr   = lane & 15;
    const int lq   = lane >> 4;
    const int KSTR = TAPS * 512;

    const int bid = blockIdx.x;
    const int n0 = (bid % GY) * TN;
    const int rem = bid / GY;
    const int t0 = (rem & 3) * 256;
    const int b  = rem >> 2;

    const int arow = tid >> 2;
    const int acol = (tid & 3) * 8;
    const unsigned short* Agh = in_hi + (size_t)b * inB + (size_t)(t0 + rowOff) * 512;
    const unsigned short* Agl = in_lo + (size_t)b * inB + (size_t)(t0 + rowOff) * 512;
    const size_t bsrc0 = (size_t)(n0 + (tid >> 2)) * KSTR + acol;

    // stage A window for channel-block c32: 10 GLDS16 per wave, uniform
    auto stageA = [&](int c32) {
        const int cc = c32 * 32;
        #pragma unroll
        for (int q = 0; q < 4; ++q) {
            size_t aoff = (size_t)(q * 64 + arow) * 512 + cc + acol;
            GLDS16(Agh + aoff, Ah_s + (q * 256 + wav * 64) * 8);
            GLDS16(Agl + aoff, Al_s + (q * 256 + wav * 64) * 8);
        }
        // tail rows 256..271: all waves stage redundantly (same data; keeps vmcnt uniform)
        size_t toff = (size_t)(256 + (lane >> 2)) * 512 + cc + (lane & 3) * 8;
        GLDS16(Agh + toff, Ah_s + 1024 * 8);
        GLDS16(Agl + toff, Al_s + 1024 * 8);
    };
    // stage B slice (c32, w) into buffer buf: 2 GLDS16 per wave
    auto stageB = [&](int c32, int w, int buf) {
        size_t src = bsrc0 + (size_t)w * 512 + c32 * 32;
        GLDS16(w_hi + src, &Bh_s[buf][wav * 512]);
        GLDS16(w_lo + src, &Bl_s[buf][wav * 512]);
    };

    float4_t acc[4][4];
    #pragma unroll
    for (int mi = 0; mi < 4; ++mi)
        #pragma unroll
        for (int nj = 0; nj < 4; ++nj) acc[mi][nj] = (float4_t)0.f;

    // prologue: A(0) [10], B(0,0)->buf0 [2]
    stageA(0);
    stageB(0, 0, 0);
    int cur = 0;

    for (int c32 = 0; c32 < 16; ++c32) {
        #pragma unroll
        for (int w = 0; w < TAPS; ++w) {
            const bool first = (w == 0);
            const bool last  = (w == TAPS - 1);
            const bool fin   = last && (c32 == 15);
            // issue next B early (into the buffer NOT read this phase)
            if (!fin) {
                int nc = last ? c32 + 1 : c32;
                int nw = last ? 0 : w + 1;
                stageB(nc, nw, cur ^ 1);
            }
            if (first) {
                if (fin) asm volatile("s_waitcnt vmcnt(0)" ::: "memory");
                else     asm volatile("s_waitcnt vmcnt(2)" ::: "memory");
                __builtin_amdgcn_s_barrier();
            }
            // fragment reads (A rows shifted by tap w; B from buf cur)
            short8_t ahf[4], alf[4], bhf[4], blf[4];
            #pragma unroll
            for (int mi = 0; mi < 4; ++mi) {
                int r = wav * 64 + mi * 16 + lr + w;
                ahf[mi] = *(const short8_t*)&Ah_s[r * 32 + lq * 8];
                alf[mi] = *(const short8_t*)&Al_s[r * 32 + lq * 8];
            }
            #pragma unroll
            for (int nj = 0; nj < 4; ++nj) {
                bhf[nj] = *(const short8_t*)&Bh_s[cur][(nj * 16 + lr) * 32 + lq * 8];
                blf[nj] = *(const short8_t*)&Bl_s[cur][(nj * 16 + lr) * 32 + lq * 8];
            }
            if (last && c32 < 15) {
                // all A-reads of this c-block complete -> safe to overwrite A
                asm volatile("s_waitcnt lgkmcnt(0)" ::: "memory");
                __builtin_amdgcn_sched_barrier(0);
                __builtin_amdgcn_s_barrier();
                stageA(c32 + 1);   // overlaps the MFMAs below
            }
            #pragma unroll
            for (int mi = 0; mi < 4; ++mi)
                #pragma unroll
                for (int nj = 0; nj < 4; ++nj) {
                    acc[mi][nj] = __builtin_amdgcn_mfma_f32_16x16x32_bf16(ahf[mi], bhf[nj], acc[mi][nj], 0, 0, 0);
                    acc[mi][nj] = __builtin_amdgcn_mfma_f32_16x16x32_bf16(alf[mi], bhf[nj], acc[mi][nj], 0, 0, 0);
                    acc[mi][nj] = __builtin_amdgcn_mfma_f32_16x16x32_bf16(ahf[mi], blf[nj], acc[mi][nj], 0, 0, 0);
                }
            if (!fin) {
                if (last && c32 < 15) asm volatile("s_waitcnt vmcnt(10)" ::: "memory");
                else                  asm volatile("s_waitcnt vmcnt(0)"  ::: "memory");
                __builtin_amdgcn_s_barrier();
            }
            cur ^= 1;
        }
    }

    if (!STATS) {
        #pragma unroll
        for (int mi = 0; mi < 4; ++mi)
            #pragma unroll
            for (int rr = 0; rr < 4; ++rr) {
                int r = t0 + wav * 64 + mi * 16 + lq * 4 + rr;
                if (r < M) {
                    #pragma unroll
                    for (int nj = 0; nj < 4; ++nj) {
                        int n = n0 + nj * 16 + lr;
                        float v = fmaxf(acc[mi][nj][rr] + bias[n], 0.f);
                        unsigned short h = f2bf(v);
                        size_t o = (size_t)b * outB + (size_t)r * N + n;
                        out_hi[o] = h;
                        out_lo[o] = f2bf(v - bf2f(h));
                    }
                }
            }
    } else {
        float cs[4] = {0.f, 0.f, 0.f, 0.f}, cq[4] = {0.f, 0.f, 0.f, 0.f};
        #pragma unroll
        for (int mi = 0; mi < 4; ++mi)
            #pragma unroll
            for (int rr = 0; rr < 4; ++rr) {
                int r = t0 + wav * 64 + mi * 16 + lq * 4 + rr;
                if (r < M) {
                    #pragma unroll
                    for (int nj = 0; nj < 4; ++nj) {
                        int n = n0 + nj * 16 + lr;
                        if (n < N) {
                            float v = fmaxf(acc[mi][nj][rr] + bias[n], 0.f);
                            cs[nj] += v;
                            cq[nj] += v * v;
                        }
                    }
                }
            }
        #pragma unroll
        for (int nj = 0; nj < 4; ++nj) {
            cs[nj] += __shfl_xor(cs[nj], 16);
            cs[nj] += __shfl_xor(cs[nj], 32);
            cq[nj] += __shfl_xor(cq[nj], 16);
            cq[nj] += __shfl_xor(cq[nj], 32);
            int n = n0 + nj * 16 + lr;
            if (lq == 0 && n < N) {
                atomicAdd(&gsum[(size_t)b * N + n], cs[nj]);
                atomicAdd(&gsq[(size_t)b * N + n], cq[nj]);
            }
        }
    }
}

// mean/std(ddof=1) -> stats [32][3000]
__global__ __launch_bounds__(256) void stats_fin_k(const float* __restrict__ sum,
                                                   const float* __restrict__ sq,
                                                   float* __restrict__ stats) {
    int idx = blockIdx.x * 256 + threadIdx.x;
    if (idx >= NB * TDNN5_) return;
    int b = idx / TDNN5_, c = idx % TDNN5_;
    float s = sum[idx], q = sq[idx];
    float n = (float)T5_;
    float mean = s / n;
    float var = (q - s * s / n) / (n - 1.f);
    stats[(size_t)b * (2 * TDNN5_) + c] = mean;
    stats[(size_t)b * (2 * TDNN5_) + TDNN5_ + c] = sqrtf(fmaxf(var, 0.f));
}

// wave-per-output FC (fp32)
__global__ __launch_bounds__(256) void fc_wave(const float* __restrict__ in,
                                               const float* __restrict__ w,
                                               const float* __restrict__ bias,
                                               float* __restrict__ out,
                                               int Bn, int N, int K4, int doRelu) {
    int wid = blockIdx.x * 4 + (threadIdx.x >> 6);
    int lane = threadIdx.x & 63;
    int b = wid / N, o = wid % N;
    if (b >= Bn) return;
    const float4* xi = (const float4*)(in + (size_t)b * K4 * 4);
    const float4* wi = (const float4*)(w + (size_t)o * K4 * 4);
    float acc = 0.f;
    for (int k = lane; k < K4; k += 64) {
        float4 xv = xi[k], wv = wi[k];
        acc += xv.x * wv.x + xv.y * wv.y + xv.z * wv.z + xv.w * wv.w;
    }
    #pragma unroll
    for (int off = 32; off > 0; off >>= 1) acc += __shfl_down(acc, off);
    if (lane == 0) {
        acc += bias[o];
        if (doRelu) acc = fmaxf(acc, 0.f);
        out[(size_t)b * N + o] = acc;
    }
}

// ---------------- launch ----------------
extern "C" void kernel_launch(void* const* d_in, const int* in_sizes, int n_in,
                              void* d_out, int out_size, void* d_ws, size_t ws_size,
                              hipStream_t stream) {
    const float* x  = (const float*)d_in[0];
    const float* k1 = (const float*)d_in[1];  const float* c1 = (const float*)d_in[2];
    const float* k2 = (const float*)d_in[3];  const float* c2 = (const float*)d_in[4];
    const float* k3 = (const float*)d_in[5];  const float* c3 = (const float*)d_in[6];
    const float* k4 = (const float*)d_in[7];  const float* c4 = (const float*)d_in[8];
    const float* k5 = (const float*)d_in[9];  const float* c5 = (const float*)d_in[10];
    const float* w1 = (const float*)d_in[11]; const float* d1 = (const float*)d_in[12];
    const float* w2 = (const float*)d_in[13]; const float* d2 = (const float*)d_in[14];
    const float* wl = (const float*)d_in[15]; const float* dl = (const float*)d_in[16];

    size_t off = 0;
    auto alloc = [&](size_t bytes) { size_t o = off; off += (bytes + 255) & ~(size_t)255; return o; };
    const size_t ACT_ELEMS = (size_t)NB * T1_ * OUT_DIM_ + 32768;
    const size_t oXHI = alloc((size_t)NB * T0_ * IN_DIM_ * 2 + 8192);
    const size_t oXLO = alloc((size_t)NB * T0_ * IN_DIM_ * 2 + 8192);
    const size_t oW1H = alloc((size_t)512 * 224 * 2 + 256);
    const size_t oW1L = alloc((size_t)512 * 224 * 2 + 256);
    const size_t oW2H = alloc((size_t)512 * 2560 * 2 + 256);
    const size_t oW2L = alloc((size_t)512 * 2560 * 2 + 256);
    const size_t oW3H = alloc((size_t)512 * 3584 * 2 + 256);
    const size_t oW3L = alloc((size_t)512 * 3584 * 2 + 256);
    const size_t oW4H = alloc((size_t)512 * 512 * 2 + 256);
    const size_t oW4L = alloc((size_t)512 * 512 * 2 + 256);
    const size_t oW5H = alloc((size_t)1536 * 512 * 2 + 256);
    const size_t oW5L = alloc((size_t)1536 * 512 * 2 + 256);
    const size_t oBAH = alloc(ACT_ELEMS * 2);
    const size_t oBAL = alloc(ACT_ELEMS * 2);
    const size_t oBBH = alloc(ACT_ELEMS * 2);
    const size_t oBBL = alloc(ACT_ELEMS * 2);
    const size_t oSUM = alloc((size_t)NB * TDNN5_ * 4);
    const size_t oSQ  = alloc((size_t)NB * TDNN5_ * 4);
    const size_t oST  = alloc((size_t)NB * 2 * TDNN5_ * 4);
    const size_t oE   = alloc((size_t)NB * 512 * 4);
    if (ws_size < off) return;

    char* W = (char*)d_ws;
    unsigned short* xhi = (unsigned short*)(W + oXHI);
    unsigned short* xlo = (unsigned short*)(W + oXLO);
    unsigned short* w1h = (unsigned short*)(W + oW1H);
    unsigned short* w1l = (unsigned short*)(W + oW1L);
    unsigned short* w2h = (unsigned short*)(W + oW2H);
    unsigned short* w2l = (unsigned short*)(W + oW2L);
    unsigned short* w3h = (unsigned short*)(W + oW3H);
    unsigned short* w3l = (unsigned short*)(W + oW3L);
    unsigned short* w4h = (unsigned short*)(W + oW4H);
    unsigned short* w4l = (unsigned short*)(W + oW4L);
    unsigned short* w5h = (unsigned short*)(W + oW5H);
    unsigned short* w5l = (unsigned short*)(W + oW5L);
    unsigned short* bah = (unsigned short*)(W + oBAH);
    unsigned short* bal = (unsigned short*)(W + oBAL);
    unsigned short* bbh = (unsigned short*)(W + oBBH);
    unsigned short* bbl = (unsigned short*)(W + oBBL);
    float* gsum  = (float*)(W + oSUM);
    float* gsq   = (float*)(W + oSQ);
    float* stats = (float*)(W + oST);
    float* evec  = (float*)(W + oE);
    float* emb  = (float*)d_out;
    float* prob = (float*)d_out + NB * 512;

    dim3 blk(256);

    // fused prep: xsplit + 5 wsplits + zero (7 launches -> 1)
    prep_all<<<(S6E + 255) / 256, blk, 0, stream>>>(
        x, k1, k2, k3, k4, k5, xhi, xlo,
        w1h, w1l, w2h, w2l, w3h, w3l, w4h, w4l, w5h, w5l, gsum);

    // L1: proven 128-tile kernel (Ci=40)
    conv_mfma<false><<<dim3(8 * 8 * NB), blk, 0, stream>>>(
        xhi, xlo, w1h, w1l, c1, bah, bal, nullptr, nullptr,
        8, T1_, 512, 224, IN_DIM_, 0, (long)T0_ * IN_DIM_, (long)T1_ * 512);
    // L2-L5: pipelined tap-aware kernel
    conv_pipe<5, false><<<dim3(4 * 8 * NB), blk, 0, stream>>>(
        bah, bal, w2h, w2l, c2, bbh, bbl, nullptr, nullptr,
        8, T2_, 512, 0, (long)T1_ * 512, (long)T2_ * 512);
    conv_pipe<7, false><<<dim3(4 * 8 * NB), blk, 0, stream>>>(
        bbh, bbl, w3h, w3l, c3, bah, bal, nullptr, nullptr,
        8, T3_, 512, 0, (long)T2_ * 512, (long)T3_ * 512);
    conv_pipe<1, false><<<dim3(4 * 8 * NB), blk, 0, stream>>>(
        bah, bal, w4h, w4l, c4, bbh, bbl, nullptr, nullptr,
        8, T4_, 512, 1, (long)T3_ * 512, (long)T4_ * 512);
    conv_pipe<1, true><<<dim3(4 * 24 * NB), blk, 0, stream>>>(
        bbh, bbl, w5h, w5l, c5, nullptr, nullptr, gsum, gsq,
        24, T5_, TDNN5_, 1, (long)T4_ * 512, 0);

    stats_fin_k<<<(NB * TDNN5_ + 255) / 256, blk, 0, stream>>>(gsum, gsq, stats);

    fc_wave<<<(NB * 512) / 4, blk, 0, stream>>>(stats, w1, d1, evec, NB, 512, 3000 / 4, 1);
    fc_wave<<<(NB * 512) / 4, blk, 0, stream>>>(evec, w2, d2, emb, NB, 512, 512 / 4, 1);
    fc_wave<<<(NB * NCLS_) / 4, blk, 0, stream>>>(emb, wl, dl, prob, NB, NCLS_, 512 / 4, 0);
}